// Round 7
// baseline (1318.186 us; speedup 1.0000x reference)
//
#include <hip/hip_runtime.h>
#include <hip/hip_fp16.h>

// Problem constants
#define NQ   2048      // N_LC == N_TE
#define NB   4         // batch
#define DD   256       // feature dim
#define M1   2049      // NQ + dustbin
#define STR  2064      // padded row stride (fp16 elems for E/ET, floats for u/v)
#define SINK_ITERS 100
#define PNWG 256       // persistent WGs (64 per batch) — <= guaranteed co-residency
#define PTPB 1024      // 16 waves per WG

typedef __attribute__((ext_vector_type(8))) short short8;
typedef __attribute__((ext_vector_type(4))) float floatx4;
typedef _Float16 h2 __attribute__((ext_vector_type(2)));

__device__ __forceinline__ unsigned short f2bf(float f) {
  unsigned u = __float_as_uint(f);
  u += 0x7FFF + ((u >> 16) & 1);   // round-to-nearest-even
  return (unsigned short)(u >> 16);
}

// ---------------- merged fp32 -> bf16 convert (all 6 inputs, vec4) ----------
// total vec4 elements: 2*(NB*NQ*DD)/4 + 4*(DD*DD)/4 = 1114112 = 4352 * 256
__global__ void k_cvt6(const float* __restrict__ x_lc, const float* __restrict__ x_te,
                       const float* __restrict__ w1lc, const float* __restrict__ w2lc,
                       const float* __restrict__ w1te, const float* __restrict__ w2te,
                       unsigned short* __restrict__ Xlc, unsigned short* __restrict__ Xte,
                       unsigned short* __restrict__ Wb) {
  const int NX4 = (NB * NQ * DD) / 4;   // 524288
  const int NW4 = (DD * DD) / 4;        // 16384
  int i4 = blockIdx.x * blockDim.x + threadIdx.x;
  const float* src; unsigned short* dst; int off;
  if (i4 < NX4)            { src = x_lc; dst = Xlc; off = i4; }
  else if (i4 < 2 * NX4)   { src = x_te; dst = Xte; off = i4 - NX4; }
  else {
    int k = i4 - 2 * NX4;
    int seg = k / NW4;
    off = k - seg * NW4;
    src = (seg == 0) ? w1lc : (seg == 1) ? w2lc : (seg == 2) ? w1te : w2te;
    dst = Wb + seg * 65536;
  }
  float4 f = ((const float4*)src)[off];
  ushort4 o;
  o.x = f2bf(f.x); o.y = f2bf(f.y); o.z = f2bf(f.z); o.w = f2bf(f.w);
  ((ushort4*)dst)[off] = o;
}

// ---------------- bf16 MFMA GEMM, C = A * B^T (both [rows x K] row-major) ----
// MODE 0: +bias, relu -> bf16          (MLP layer 1; bias selected by blockIdx.z)
// MODE 1: +bias       -> bf16          (MLP layer 2; bias selected by blockIdx.z)
// MODE 2: *1/16, clamp, exp -> fp16    (scores -> E or ET)
template<int MODE>
__global__ __launch_bounds__(256, 2)
void k_gemm_bt(const unsigned short* __restrict__ A,
               const unsigned short* __restrict__ Bt,
               void* __restrict__ Out,
               const float* __restrict__ bias, const float* __restrict__ bias2,
               int K, long aBatch, long bBatch, long oBatch, int ostride)
{
  __shared__ __align__(16) unsigned short lA[128 * 32];
  __shared__ __align__(16) unsigned short lB[128 * 32];
  const int tid  = threadIdx.x;
  const int lane = tid & 63;
  const int w    = tid >> 6;
  const int wm   = (w >> 1) * 64;
  const int wn   = (w & 1) * 64;
  const long bz  = blockIdx.z;
  const unsigned short* Ab = A  + bz * aBatch + (long)blockIdx.y * 128 * K;
  const unsigned short* Bb = Bt + bz * bBatch + (long)blockIdx.x * 128 * K;
  const float* bp = (bz == 0) ? bias : bias2;

  floatx4 acc[4][4];
  #pragma unroll
  for (int i = 0; i < 4; i++)
    #pragma unroll
    for (int j = 0; j < 4; j++) acc[i][j] = (floatx4){0.f, 0.f, 0.f, 0.f};

  for (int kt = 0; kt < K; kt += 32) {
    __syncthreads();
    #pragma unroll
    for (int s0 = 0; s0 < 512; s0 += 256) {
      int s = s0 + tid;
      int row = s >> 2, part = s & 3;
      ((uint4*)lA)[s] = *(const uint4*)(Ab + (long)row * K + kt + part * 8);
      ((uint4*)lB)[s] = *(const uint4*)(Bb + (long)row * K + kt + part * 8);
    }
    __syncthreads();
    const int kq = (lane >> 4) * 8;
    const int rl = lane & 15;
    short8 af[4], bf[4];
    #pragma unroll
    for (int t = 0; t < 4; t++) {
      af[t] = *(const short8*)(lA + (wm + t * 16 + rl) * 32 + kq);
      bf[t] = *(const short8*)(lB + (wn + t * 16 + rl) * 32 + kq);
    }
    #pragma unroll
    for (int i = 0; i < 4; i++)
      #pragma unroll
      for (int j = 0; j < 4; j++)
        acc[i][j] = __builtin_amdgcn_mfma_f32_16x16x32_bf16(af[i], bf[j], acc[i][j], 0, 0, 0);
  }

  // epilogue — C/D layout: col = lane&15, row = (lane>>4)*4 + reg
  const int cl = lane & 15, qd = lane >> 4;
  #pragma unroll
  for (int i = 0; i < 4; i++)
    #pragma unroll
    for (int j = 0; j < 4; j++) {
      const int col = blockIdx.x * 128 + wn + j * 16 + cl;
      const float bcol = (MODE >= 2) ? 0.f : bp[col];
      #pragma unroll
      for (int r = 0; r < 4; r++) {
        const long row = (long)blockIdx.y * 128 + wm + i * 16 + qd * 4 + r;
        float v = acc[i][j][r];
        if (MODE == 0) {
          v += bcol; v = v > 0.f ? v : 0.f;
          ((unsigned short*)Out)[bz * oBatch + row * ostride + col] = f2bf(v);
        } else if (MODE == 1) {
          v += bcol;
          ((unsigned short*)Out)[bz * oBatch + row * ostride + col] = f2bf(v);
        } else {
          v *= 0.0625f;                       // 1/sqrt(256)
          v = fminf(fmaxf(v, -15.f), 10.9f);  // e^10.9 = 54k < fp16 max 65504
          ((__half*)Out)[bz * oBatch + row * ostride + col] = __float2half(__expf(v));
        }
      }
    }
}

// ---------------- fill E dustbin row/col + init ev = 1 + zero barrier --------
__global__ void k_fillinit(__half* __restrict__ E, const float* __restrict__ alphaPtr,
                           float* __restrict__ ev, unsigned* __restrict__ bar) {
  const float ea = __expf(*alphaPtr);
  const int idx = blockIdx.x * blockDim.x + threadIdx.x;
  const int n1 = NB * NQ * 16;  // rows 0..2047, cols 2048..2063
  if (idx < n1) {
    int b = idx / (NQ * 16);
    int rr = idx - b * NQ * 16;
    int i = rr >> 4;
    int j = 2048 + (rr & 15);
    E[((long)b * M1 + i) * STR + j] = (j == 2048) ? __float2half(ea) : __float2half(0.f);
  } else {
    int k = idx - n1;             // dustbin row: NB * STR entries
    if (k < NB * STR) {
      int b = k / STR;
      int j = k - b * STR;
      E[((long)b * M1 + 2048) * STR + j] = (j <= 2048) ? __float2half(ea) : __float2half(0.f);
    }
  }
  if (idx < NB * STR) ev[idx] = 1.0f;
  if (idx < 2048) bar[idx] = 0u;   // 4 batches x {cnt, gen} on separate 128B lines
}

// ---------------- agent-scope relaxed helpers (NO cache invalidates) ---------
__device__ __forceinline__ void st_agent(float* p, float v) {
  __hip_atomic_store(p, v, __ATOMIC_RELAXED, __HIP_MEMORY_SCOPE_AGENT);
}
__device__ __forceinline__ float ld_agent(const float* p) {
  return __hip_atomic_load(p, __ATOMIC_RELAXED, __HIP_MEMORY_SCOPE_AGENT);
}
__device__ __forceinline__ unsigned ld_u32_agent(const unsigned* p) {
  return __hip_atomic_load(p, __ATOMIC_RELAXED, __HIP_MEMORY_SCOPE_AGENT);
}

__device__ __forceinline__ float wave_sum(float s) {
  #pragma unroll
  for (int o = 32; o; o >>= 1) s += __shfl_xor(s, o);
  return s;
}

// dot of 8 fp16 values (packed in a uint4) with 8 fp16 weights at wp[0..3] (h2)
__device__ __forceinline__ float dot8h(uint4 hv, const h2* wp, float s) {
  const h2* e = (const h2*)&hv;
#if __has_builtin(__builtin_amdgcn_fdot2)
  #pragma unroll
  for (int q = 0; q < 4; q++)
    s = __builtin_amdgcn_fdot2(e[q], wp[q], s, false);   // v_dot2_f32_f16
#else
  #pragma unroll
  for (int q = 0; q < 4; q++) {
    float2 a = __half22float2(*(const __half2*)&e[q]);
    float2 b = __half22float2(*(const __half2*)&wp[q]);
    s = fmaf(a.x, b.x, fmaf(a.y, b.y, s));
  }
#endif
  return s;
}

// ---------------- persistent Sinkhorn, plain launch (NOT cooperative) --------
// R0/R6 codegen shape preserved (load-bearing: no lambda, row loads issued
// AFTER the staging __syncthreads, tid0-only scalar poll). R6 barrier kept
// (flat arrive + last-man gen broadcast on a separate 128B line; 806us, vs
// tree 887 / flat-same-line 925).
//
// R7 change: sweep matrices are fp16 (E, ET — E reused from k_final input),
// consumed via v_dot2_f32_f16 (fdot2, fp32 accumulate): 32 fdot2 replace ~96
// cvt/fma VALU ops per lane per phase, and LDS weight reads halve.
// Staged u/v are scaled by 4096 before fp16 conversion: the alternating
// iteration's gauge puts u ~ 1.2e-7 (fp16 subnormal!); x4096 -> ~5e-4,
// comfortably normal. Denominators rescale analytically:
//   u_r = (1/4096)/(a + ea*d)  ->  1/(a_s + ea*d_s)      (a_s = 4096*a)
//   dust = 0.5/(ea*(S + d))    ->  2048/(ea*(S_s + d_s))
__global__ __launch_bounds__(PTPB, 4)
void k_sink(const __half* __restrict__ Eh, const __half* __restrict__ ETh,
            float* __restrict__ eu, float* __restrict__ ev,
            const float* __restrict__ alphaPtr, unsigned* __restrict__ bar)
{
  __shared__ __align__(16) __half svh[2048];   // staged vector * 4096, fp16
  __shared__ float sdust;                      // staged v[2048] * 4096, fp32
  const int tid  = threadIdx.x;
  const int wg   = blockIdx.x;
  const int b    = wg >> 6;          // batch 0..3
  const int g    = wg & 63;          // group within batch
  const int wv   = tid >> 6;         // wave 0..15
  const int lane = tid & 63;
  const int r0   = (g * 16 + wv) * 2;   // rows r0, r0+1 in [0, 2048)
  const float ea = __expf(alphaPtr[0]);
  const __half* Er  = Eh  + ((long)b * M1 + r0) * STR;
  const __half* ETr = ETh + ((long)b * M1 + r0) * STR;
  float* ub = eu + b * STR;
  float* vb = ev + b * STR;
  unsigned* cnt = bar + b * 64;       // per-batch arrive counter
  unsigned* gen = bar + b * 64 + 32;  // release word, separate 128B line
  const bool dustwave = (g == 63) && (wv == 15);

  unsigned phase = 0;
  for (int it = 0; it < 2 * SINK_ITERS; ++it) {
    const __half* R = (it & 1) ? ETr : Er;
    const float* vin = (it & 1) ? ub : vb;
    float*      vout = (it & 1) ? vb : ub;

    // stage vin*4096 -> fp16 LDS (sc1: fresh from LLC; 2 rounds + tid0 dust)
    for (int j = tid; j < 2048; j += PTPB)
      svh[j] = __float2half(ld_agent(vin + j) * 4096.f);
    if (tid == 0) sdust = ld_agent(vin + 2048) * 4096.f;
    __syncthreads();

    // two fp16 rows per wave, 32 B per lane per 1024-col chunk
    uint4 e00 = *(const uint4*)(R +        lane * 16);
    uint4 e01 = *(const uint4*)(R +        lane * 16 + 8);
    uint4 e02 = *(const uint4*)(R + 1024 + lane * 16);
    uint4 e03 = *(const uint4*)(R + 1024 + lane * 16 + 8);
    uint4 e10 = *(const uint4*)(R + STR  +        lane * 16);
    uint4 e11 = *(const uint4*)(R + STR  +        lane * 16 + 8);
    uint4 e12 = *(const uint4*)(R + STR  + 1024 + lane * 16);
    uint4 e13 = *(const uint4*)(R + STR  + 1024 + lane * 16 + 8);
    const h2* wp0 = (const h2*)(svh +        lane * 16);
    const h2* wp1 = (const h2*)(svh + 1024 + lane * 16);
    float a0 = dot8h(e00, wp0, 0.f);
    a0 = dot8h(e01, wp0 + 4, a0);
    a0 = dot8h(e02, wp1, a0);
    a0 = dot8h(e03, wp1 + 4, a0);
    float a1 = dot8h(e10, wp0, 0.f);
    a1 = dot8h(e11, wp0 + 4, a1);
    a1 = dot8h(e12, wp1, a1);
    a1 = dot8h(e13, wp1 + 4, a1);
    a0 = wave_sum(a0);
    a1 = wave_sum(a1);
    if (lane == 0) {
      const float wd = ea * sdust;             // dustbin column contribution
      st_agent(vout + r0,     1.f / (a0 + wd));
      st_agent(vout + r0 + 1, 1.f / (a1 + wd));
    }

    // dustbin row analytic: vout[2048] = 2048 / (ea * (S_s + d_s))
    if (dustwave) {
      float s = 0.f;
      const __half2* p0 = (const __half2*)(svh +        lane * 16);
      const __half2* p1 = (const __half2*)(svh + 1024 + lane * 16);
      #pragma unroll
      for (int q = 0; q < 8; q++) {
        float2 x = __half22float2(p0[q]);
        float2 y = __half22float2(p1[q]);
        s += x.x + x.y + y.x + y.y;
      }
      s = wave_sum(s);
      if (lane == 0) st_agent(vout + 2048, 2048.f / (ea * (s + sdust)));
    }

    // ---- per-batch barrier: flat arrive + last-man gen broadcast ----
    ++phase;
    __syncthreads();   // drains vmcnt: this WG's sc1 stores are at LLC
    if (tid == 0) {
      unsigned old = __hip_atomic_fetch_add(cnt, 1u, __ATOMIC_RELAXED, __HIP_MEMORY_SCOPE_AGENT);
      if (old == phase * 64u - 1u) {
        __hip_atomic_store(gen, phase, __ATOMIC_RELAXED, __HIP_MEMORY_SCOPE_AGENT);
      } else {
        while (ld_u32_agent(gen) < phase)
          __builtin_amdgcn_s_sleep(1);
      }
    }
    __syncthreads();
  }
}

// ---------------- finalize: out = E * eu * ev * 4096 (fp16 E) ----------------
__global__ void k_final(const __half* __restrict__ E, const float* __restrict__ eu,
                        const float* __restrict__ ev, float* __restrict__ out) {
  const int wv = blockIdx.x;      // NB * M1 rows
  const int b = wv / M1;
  const int i = wv - b * M1;
  const __half* R = E + ((long)b * M1 + i) * STR;
  const float ui = eu[b * STR + i] * 4096.f;   // * exp(-norm)
  const float* evb = ev + b * STR;
  float* orow = out + ((long)b * M1 + i) * M1;
  for (int j = threadIdx.x; j < M1; j += blockDim.x)
    orow[j] = __half2float(R[j]) * ui * evb[j];
}

// ---------------- launch -----------------------------------------------------
extern "C" void kernel_launch(void* const* d_in, const int* in_sizes, int n_in,
                              void* d_out, int out_size, void* d_ws, size_t ws_size,
                              hipStream_t stream) {
  const float* x_lc  = (const float*)d_in[0];
  const float* x_te  = (const float*)d_in[1];
  const float* W1_lc = (const float*)d_in[2];
  const float* b1_lc = (const float*)d_in[3];
  const float* W2_lc = (const float*)d_in[4];
  const float* b2_lc = (const float*)d_in[5];
  const float* W1_te = (const float*)d_in[6];
  const float* b1_te = (const float*)d_in[7];
  const float* W2_te = (const float*)d_in[8];
  const float* b2_te = (const float*)d_in[9];
  const float* alpha = (const float*)d_in[10];

  char* ws = (char*)d_ws;
  unsigned short* Xlc = (unsigned short*)(ws + 0);          //  4 MB (reused as F1)
  unsigned short* Wb  = (unsigned short*)(ws + 8388608);    //  0.5 MB
  unsigned short* H   = (unsigned short*)(ws + 8912896);    //  8 MB (both MLP chains)
  unsigned short* F   = (unsigned short*)(ws + 0);          //  8 MB (F1 @0, F2 @4MB)
  __half* E  = (__half*)(ws + 21495808);                    // 33.83 MB fp16
  __half* ET = (__half*)(ws + 55328896);                    // 33.83 MB fp16 (transposed)
  float* eu  = (float*)(ws + 89161984);                     // 4 x 2064 f32
  float* ev  = (float*)(ws + 89195008);                     // 4 x 2064 f32
  unsigned* bar = (unsigned*)(ws + 89228032);               // 8 KB barrier state

  unsigned short* Xte = Xlc + 2097152;   // ws + 4 MB

  // merged fp32->bf16 conversion of all six inputs (one launch, vec4)
  k_cvt6<<<4352, 256, 0, stream>>>(x_lc, x_te, W1_lc, W2_lc, W1_te, W2_te,
                                   Xlc, Xte, Wb);

  // MLPs: lc and te chains merged via blockIdx.z (z=0: lc, z=1: te).
  // A batches contiguous (Xlc/Xte), W batches at stride 131072, H/F at 2097152.
  k_gemm_bt<0><<<dim3(2, 64, 2), 256, 0, stream>>>(Xlc, Wb,          H, b1_lc, b1_te,
                                                   DD, 2097152, 131072, 2097152, DD);
  k_gemm_bt<1><<<dim3(2, 64, 2), 256, 0, stream>>>(H,   Wb + 65536,  F, b2_lc, b2_te,
                                                   DD, 2097152, 131072, 2097152, DD);

  // scores -> E (fp16) and ET (fp16, transposed), per batch
  unsigned short* F1 = F;
  unsigned short* F2 = F + 2097152;
  const long ab = (long)NQ * DD;        // 524288
  const long ob = (long)M1 * STR;       // 4229136 elems
  k_gemm_bt<2><<<dim3(16, 16, NB), 256, 0, stream>>>(F1, F2, E,  nullptr, nullptr, DD, ab, ab, ob, STR);
  k_gemm_bt<2><<<dim3(16, 16, NB), 256, 0, stream>>>(F2, F1, ET, nullptr, nullptr, DD, ab, ab, ob, STR);

  // E dustbin row/col + ev = 1 + barrier = 0 (one launch)
  const int nfill = NB * NQ * 16 + NB * STR;  // 139328
  k_fillinit<<<(nfill + 255) / 256, 256, 0, stream>>>(E, alpha, ev, bar);

  // persistent Sinkhorn: ONE plain launch, fixed 100 iterations
  k_sink<<<PNWG, PTPB, 0, stream>>>(E, ET, eu, ev, alpha, bar);

  // out = E * eu * ev * (m+n)
  k_final<<<NB * M1, 256, 0, stream>>>(E, eu, ev, (float*)d_out);
}

// Round 8
// 878.101 us; speedup vs baseline: 1.5012x; 1.5012x over previous
//
#include <hip/hip_runtime.h>
#include <hip/hip_fp16.h>

// Problem constants
#define NQ   2048      // N_LC == N_TE
#define NB   4         // batch
#define DD   256       // feature dim
#define M1   2049      // NQ + dustbin
#define STR  2064      // padded row stride (fp16 elems for E, bytes for E8/ET8, floats for u/v)
#define SINK_ITERS 100
#define PNWG 256       // persistent WGs (64 per batch) — <= guaranteed co-residency (1/CU)
#define PTPB 1024      // 16 waves per WG

typedef __attribute__((ext_vector_type(8))) short short8;
typedef __attribute__((ext_vector_type(4))) float floatx4;
typedef __attribute__((ext_vector_type(2))) float floatx2;

__device__ __forceinline__ unsigned short f2bf(float f) {
  unsigned u = __float_as_uint(f);
  u += 0x7FFF + ((u >> 16) & 1);   // round-to-nearest-even
  return (unsigned short)(u >> 16);
}

// fp32 -> fp8 e5m2 (OCP): e5m2 == top byte of IEEE half, RN
__device__ __forceinline__ unsigned char f2fp8(float f) {
  unsigned short u = __half_as_ushort(__float2half(f));
  return (unsigned char)((u + 0x7F + ((u >> 8) & 1)) >> 8);
}

// swizzled LDS index: pad 1 float per 16 -> lane stride 17 floats (2-way = free)
__device__ __forceinline__ int IDX(int j) { return j + (j >> 4); }

// ---------------- merged fp32 -> bf16 convert (all 6 inputs, vec4) ----------
// total vec4 elements: 2*(NB*NQ*DD)/4 + 4*(DD*DD)/4 = 1114112 = 4352 * 256
__global__ void k_cvt6(const float* __restrict__ x_lc, const float* __restrict__ x_te,
                       const float* __restrict__ w1lc, const float* __restrict__ w2lc,
                       const float* __restrict__ w1te, const float* __restrict__ w2te,
                       unsigned short* __restrict__ Xlc, unsigned short* __restrict__ Xte,
                       unsigned short* __restrict__ Wb) {
  const int NX4 = (NB * NQ * DD) / 4;   // 524288
  const int NW4 = (DD * DD) / 4;        // 16384
  int i4 = blockIdx.x * blockDim.x + threadIdx.x;
  const float* src; unsigned short* dst; int off;
  if (i4 < NX4)            { src = x_lc; dst = Xlc; off = i4; }
  else if (i4 < 2 * NX4)   { src = x_te; dst = Xte; off = i4 - NX4; }
  else {
    int k = i4 - 2 * NX4;
    int seg = k / NW4;
    off = k - seg * NW4;
    src = (seg == 0) ? w1lc : (seg == 1) ? w2lc : (seg == 2) ? w1te : w2te;
    dst = Wb + seg * 65536;
  }
  float4 f = ((const float4*)src)[off];
  ushort4 o;
  o.x = f2bf(f.x); o.y = f2bf(f.y); o.z = f2bf(f.z); o.w = f2bf(f.w);
  ((ushort4*)dst)[off] = o;
}

// ---------------- bf16 MFMA GEMM, C = A * B^T (both [rows x K] row-major) ----
// MODE 0: +bias, relu -> bf16          (MLP layer 1; bias selected by blockIdx.z)
// MODE 1: +bias       -> bf16          (MLP layer 2; bias selected by blockIdx.z)
// MODE 2: *1/16, clamp, exp -> fp16 E AND fp8 e5m2 E8
// MODE 3: *1/16, clamp, exp -> fp8 e5m2 ET8 only
template<int MODE>
__global__ __launch_bounds__(256, 2)
void k_gemm_bt(const unsigned short* __restrict__ A,
               const unsigned short* __restrict__ Bt,
               void* __restrict__ Out, void* __restrict__ Out8,
               const float* __restrict__ bias, const float* __restrict__ bias2,
               int K, long aBatch, long bBatch, long oBatch, int ostride)
{
  __shared__ __align__(16) unsigned short lA[128 * 32];
  __shared__ __align__(16) unsigned short lB[128 * 32];
  const int tid  = threadIdx.x;
  const int lane = tid & 63;
  const int w    = tid >> 6;
  const int wm   = (w >> 1) * 64;
  const int wn   = (w & 1) * 64;
  const long bz  = blockIdx.z;
  const unsigned short* Ab = A  + bz * aBatch + (long)blockIdx.y * 128 * K;
  const unsigned short* Bb = Bt + bz * bBatch + (long)blockIdx.x * 128 * K;
  const float* bp = (bz == 0) ? bias : bias2;

  floatx4 acc[4][4];
  #pragma unroll
  for (int i = 0; i < 4; i++)
    #pragma unroll
    for (int j = 0; j < 4; j++) acc[i][j] = (floatx4){0.f, 0.f, 0.f, 0.f};

  for (int kt = 0; kt < K; kt += 32) {
    __syncthreads();
    #pragma unroll
    for (int s0 = 0; s0 < 512; s0 += 256) {
      int s = s0 + tid;
      int row = s >> 2, part = s & 3;
      ((uint4*)lA)[s] = *(const uint4*)(Ab + (long)row * K + kt + part * 8);
      ((uint4*)lB)[s] = *(const uint4*)(Bb + (long)row * K + kt + part * 8);
    }
    __syncthreads();
    const int kq = (lane >> 4) * 8;
    const int rl = lane & 15;
    short8 af[4], bf[4];
    #pragma unroll
    for (int t = 0; t < 4; t++) {
      af[t] = *(const short8*)(lA + (wm + t * 16 + rl) * 32 + kq);
      bf[t] = *(const short8*)(lB + (wn + t * 16 + rl) * 32 + kq);
    }
    #pragma unroll
    for (int i = 0; i < 4; i++)
      #pragma unroll
      for (int j = 0; j < 4; j++)
        acc[i][j] = __builtin_amdgcn_mfma_f32_16x16x32_bf16(af[i], bf[j], acc[i][j], 0, 0, 0);
  }

  // epilogue — C/D layout: col = lane&15, row = (lane>>4)*4 + reg
  const int cl = lane & 15, qd = lane >> 4;
  #pragma unroll
  for (int i = 0; i < 4; i++)
    #pragma unroll
    for (int j = 0; j < 4; j++) {
      const int col = blockIdx.x * 128 + wn + j * 16 + cl;
      const float bcol = (MODE >= 2) ? 0.f : bp[col];
      #pragma unroll
      for (int r = 0; r < 4; r++) {
        const long row = (long)blockIdx.y * 128 + wm + i * 16 + qd * 4 + r;
        float v = acc[i][j][r];
        if (MODE == 0) {
          v += bcol; v = v > 0.f ? v : 0.f;
          ((unsigned short*)Out)[bz * oBatch + row * ostride + col] = f2bf(v);
        } else if (MODE == 1) {
          v += bcol;
          ((unsigned short*)Out)[bz * oBatch + row * ostride + col] = f2bf(v);
        } else {
          v *= 0.0625f;                       // 1/sqrt(256)
          v = fminf(fmaxf(v, -15.f), 10.9f);  // e^10.9 = 54k < e5m2 max 57344
          float e = __expf(v);
          const long idx = bz * oBatch + row * ostride + col;
          if (MODE == 2) ((__half*)Out)[idx] = __float2half(e);
          ((unsigned char*)Out8)[idx] = f2fp8(e);
        }
      }
    }
}

// ---------------- fill E dustbin row/col + init ev = 1 + zero barrier --------
__global__ void k_fillinit(__half* __restrict__ E, const float* __restrict__ alphaPtr,
                           float* __restrict__ ev, unsigned* __restrict__ bar) {
  const float ea = __expf(*alphaPtr);
  const int idx = blockIdx.x * blockDim.x + threadIdx.x;
  const int n1 = NB * NQ * 16;  // rows 0..2047, cols 2048..2063
  if (idx < n1) {
    int b = idx / (NQ * 16);
    int rr = idx - b * NQ * 16;
    int i = rr >> 4;
    int j = 2048 + (rr & 15);
    E[((long)b * M1 + i) * STR + j] = (j == 2048) ? __float2half(ea) : __float2half(0.f);
  } else {
    int k = idx - n1;             // dustbin row: NB * STR entries
    if (k < NB * STR) {
      int b = k / STR;
      int j = k - b * STR;
      E[((long)b * M1 + 2048) * STR + j] = (j <= 2048) ? __float2half(ea) : __float2half(0.f);
    }
  }
  if (idx < NB * STR) ev[idx] = 1.0f;
  if (idx < 2048) bar[idx] = 0u;   // 4 batches x {cnt, gen} on separate 128B lines
}

// ---------------- agent-scope relaxed helpers (NO cache invalidates) ---------
__device__ __forceinline__ void st_agent(float* p, float v) {
  __hip_atomic_store(p, v, __ATOMIC_RELAXED, __HIP_MEMORY_SCOPE_AGENT);
}
__device__ __forceinline__ float ld_agent(const float* p) {
  return __hip_atomic_load(p, __ATOMIC_RELAXED, __HIP_MEMORY_SCOPE_AGENT);
}
__device__ __forceinline__ unsigned ld_u32_agent(const unsigned* p) {
  return __hip_atomic_load(p, __ATOMIC_RELAXED, __HIP_MEMORY_SCOPE_AGENT);
}

__device__ __forceinline__ float wave_sum(float s) {
  #pragma unroll
  for (int o = 32; o; o >>= 1) s += __shfl_xor(s, o);
  return s;
}

// dot of 16 fp8(e5m2) values with 16 fp32 weights at wp[0..15]
__device__ __forceinline__ float dot16f8(uint4 hv, const float* wp) {
  const unsigned* u = (const unsigned*)&hv;
  float s = 0.f;
#if __has_builtin(__builtin_amdgcn_cvt_pk_f32_bf8)
  #pragma unroll
  for (int q = 0; q < 4; q++) {
    floatx2 lo = __builtin_amdgcn_cvt_pk_f32_bf8((int)u[q], false);
    floatx2 hi = __builtin_amdgcn_cvt_pk_f32_bf8((int)u[q], true);
    s += lo.x * wp[q * 4 + 0] + lo.y * wp[q * 4 + 1]
       + hi.x * wp[q * 4 + 2] + hi.y * wp[q * 4 + 3];
  }
#else
  const unsigned char* p = (const unsigned char*)&hv;
  #pragma unroll
  for (int t = 0; t < 16; t++) {
    unsigned short h = (unsigned short)p[t] << 8;
    s += __half2float(*reinterpret_cast<__half*>(&h)) * wp[t];
  }
#endif
  return s;
}

// ---------------- persistent Sinkhorn, plain launch (NOT cooperative) --------
// R6 numerics (fp8 e5m2 rows, fp32 stride-17 sv — fp16 rows blew the 4MB/XCD
// L2 budget in R7: FETCH 1.26->3.03GB) + R6 barrier (flat arrive + last-man
// gen broadcast on a separate 128B line). Codegen shape rules preserved:
// no lambda, tid0-only scalar poll, row reads after the staging sync.
//
// R8 change: each wave's 4 rows (2 E8 + 2 ET8, 2KB each) are copied to LDS
// ONCE in the prologue and read from LDS for all 200 phases -> zero row
// traffic to L2/HBM in the loop. Per-WG LDS: 128KB rows + 8.8KB sv = 136.8KB
// (<160KB, 1 WG/CU; grid 256 = CU count so co-residency holds). Each wave
// reads only its OWN rows -> no barrier needed for the row cache.
__global__ __launch_bounds__(PTPB, 4)
void k_sink(const unsigned char* __restrict__ E8, const unsigned char* __restrict__ ET8,
            float* __restrict__ eu, float* __restrict__ ev,
            const float* __restrict__ alphaPtr, unsigned* __restrict__ bar)
{
  __shared__ __align__(16) unsigned char rows[131072];  // [wave][E|ET][2 rows][2048]
  __shared__ __align__(16) float sv[2200];              // swizzled vector (2064 + pads)
  const int tid  = threadIdx.x;
  const int wg   = blockIdx.x;
  const int b    = wg >> 6;          // batch 0..3
  const int g    = wg & 63;          // group within batch
  const int wv   = tid >> 6;         // wave 0..15
  const int lane = tid & 63;
  const int r0   = (g * 16 + wv) * 2;   // rows r0, r0+1 in [0, 2048)
  const float ea = __expf(alphaPtr[0]);
  const unsigned char* E8r  = E8  + ((long)b * M1 + r0) * STR;
  const unsigned char* ET8r = ET8 + ((long)b * M1 + r0) * STR;
  float* ub = eu + b * STR;
  float* vb = ev + b * STR;
  unsigned* cnt = bar + b * 64;       // per-batch arrive counter
  unsigned* gen = bar + b * 64 + 32;  // release word, separate 128B line
  const bool dustwave = (g == 63) && (wv == 15);

  // prologue: pin this wave's 4 rows in LDS (read once from L2/HBM)
  {
    uint4* dw = (uint4*)(rows + wv * 8192);
    dw[lane]       = *(const uint4*)(E8r  +        lane * 16);
    dw[64 + lane]  = *(const uint4*)(E8r  + 1024 + lane * 16);
    dw[128 + lane] = *(const uint4*)(E8r  + STR  +        lane * 16);
    dw[192 + lane] = *(const uint4*)(E8r  + STR  + 1024 + lane * 16);
    dw[256 + lane] = *(const uint4*)(ET8r +        lane * 16);
    dw[320 + lane] = *(const uint4*)(ET8r + 1024 + lane * 16);
    dw[384 + lane] = *(const uint4*)(ET8r + STR  +        lane * 16);
    dw[448 + lane] = *(const uint4*)(ET8r + STR  + 1024 + lane * 16);
  }

  unsigned phase = 0;
  for (int it = 0; it < 2 * SINK_ITERS; ++it) {
    const float* vin = (it & 1) ? ub : vb;
    float*      vout = (it & 1) ? vb : ub;

    // stage vin -> swizzled LDS (sc1: fresh from LLC; 3 rounds, tid0 gets 2048)
    for (int j = tid; j < M1; j += PTPB) sv[IDX(j)] = ld_agent(vin + j);
    __syncthreads();

    // two fp8 rows per wave from the LDS row cache, 16 bytes/lane per chunk
    const unsigned char* Rl = rows + wv * 8192 + ((it & 1) << 12);
    uint4 h0c0 = *(const uint4*)(Rl +        lane * 16);
    uint4 h0c1 = *(const uint4*)(Rl + 1024 + lane * 16);
    uint4 h1c0 = *(const uint4*)(Rl + 2048 + lane * 16);
    uint4 h1c1 = *(const uint4*)(Rl + 3072 + lane * 16);
    const float* w0 = sv + lane * 17;          // IDX(lane*16)
    const float* w1 = sv + 1088 + lane * 17;   // IDX(1024 + lane*16)
    float a0 = dot16f8(h0c0, w0) + dot16f8(h0c1, w1);
    float a1 = dot16f8(h1c0, w0) + dot16f8(h1c1, w1);
    a0 = wave_sum(a0);
    a1 = wave_sum(a1);
    if (lane == 0) {
      const float wd = ea * sv[IDX(2048)];     // dustbin column (value == ea)
      st_agent(vout + r0,     (1.f / 4096.f) / (a0 + wd));
      st_agent(vout + r0 + 1, (1.f / 4096.f) / (a1 + wd));
    }

    // dustbin row analytic: vout[2048] = 0.5 / (ea * sum(vin))
    if (dustwave) {
      float s = 0.f;
      #pragma unroll
      for (int t = 0; t < 16; t++) s += w0[t] + w1[t];
      s = wave_sum(s);
      if (lane == 0) st_agent(vout + 2048, 0.5f / (ea * (s + sv[IDX(2048)])));
    }

    // ---- per-batch barrier: flat arrive + last-man gen broadcast ----
    ++phase;
    __syncthreads();   // drains vmcnt: this WG's sc1 stores are at LLC
    if (tid == 0) {
      unsigned old = __hip_atomic_fetch_add(cnt, 1u, __ATOMIC_RELAXED, __HIP_MEMORY_SCOPE_AGENT);
      if (old == phase * 64u - 1u) {
        __hip_atomic_store(gen, phase, __ATOMIC_RELAXED, __HIP_MEMORY_SCOPE_AGENT);
      } else {
        while (ld_u32_agent(gen) < phase)
          __builtin_amdgcn_s_sleep(1);
      }
    }
    __syncthreads();
  }
}

// ---------------- finalize: out = E * eu * ev * 4096 (fp16 E) ----------------
__global__ void k_final(const __half* __restrict__ E, const float* __restrict__ eu,
                        const float* __restrict__ ev, float* __restrict__ out) {
  const int wv = blockIdx.x;      // NB * M1 rows
  const int b = wv / M1;
  const int i = wv - b * M1;
  const __half* R = E + ((long)b * M1 + i) * STR;
  const float ui = eu[b * STR + i] * 4096.f;   // * exp(-norm)
  const float* evb = ev + b * STR;
  float* orow = out + ((long)b * M1 + i) * M1;
  for (int j = threadIdx.x; j < M1; j += blockDim.x)
    orow[j] = __half2float(R[j]) * ui * evb[j];
}

// ---------------- launch -----------------------------------------------------
extern "C" void kernel_launch(void* const* d_in, const int* in_sizes, int n_in,
                              void* d_out, int out_size, void* d_ws, size_t ws_size,
                              hipStream_t stream) {
  const float* x_lc  = (const float*)d_in[0];
  const float* x_te  = (const float*)d_in[1];
  const float* W1_lc = (const float*)d_in[2];
  const float* b1_lc = (const float*)d_in[3];
  const float* W2_lc = (const float*)d_in[4];
  const float* b2_lc = (const float*)d_in[5];
  const float* W1_te = (const float*)d_in[6];
  const float* b1_te = (const float*)d_in[7];
  const float* W2_te = (const float*)d_in[8];
  const float* b2_te = (const float*)d_in[9];
  const float* alpha = (const float*)d_in[10];

  char* ws = (char*)d_ws;
  unsigned short* Xlc = (unsigned short*)(ws + 0);          //  4 MB (later reused as F1)
  unsigned short* Wb  = (unsigned short*)(ws + 8388608);    //  0.5 MB
  unsigned short* H   = (unsigned short*)(ws + 8912896);    //  8 MB (both MLP chains)
  unsigned short* F   = (unsigned short*)(ws + 0);          //  8 MB (F1 @0, F2 @4MB)
  __half* E  = (__half*)(ws + 21495808);                    // 33.83 MB fp16 (final)
  unsigned char* E8  = (unsigned char*)(ws + 55328896);     // 16.92 MB fp8 (sweep)
  unsigned char* ET8 = (unsigned char*)(ws + 72245440);     // 16.92 MB fp8 (sweep)
  float* eu  = (float*)(ws + 89161984);                     // 4 x 2064 f32
  float* ev  = (float*)(ws + 89195008);                     // 4 x 2064 f32
  unsigned* bar = (unsigned*)(ws + 89228032);               // 8 KB barrier state

  unsigned short* Xte = Xlc + 2097152;   // ws + 4 MB

  // merged fp32->bf16 conversion of all six inputs (one launch, vec4)
  k_cvt6<<<4352, 256, 0, stream>>>(x_lc, x_te, W1_lc, W2_lc, W1_te, W2_te,
                                   Xlc, Xte, Wb);

  // MLPs: lc and te chains merged via blockIdx.z (z=0: lc, z=1: te).
  k_gemm_bt<0><<<dim3(2, 64, 2), 256, 0, stream>>>(Xlc, Wb,         H, nullptr, b1_lc, b1_te,
                                                   DD, 2097152, 131072, 2097152, DD);
  k_gemm_bt<1><<<dim3(2, 64, 2), 256, 0, stream>>>(H,   Wb + 65536, F, nullptr, b2_lc, b2_te,
                                                   DD, 2097152, 131072, 2097152, DD);

  // scores -> E (fp16+fp8) and ET (fp8 only), per batch
  unsigned short* F1 = F;
  unsigned short* F2 = F + 2097152;
  const long ab = (long)NQ * DD;        // 524288
  const long ob = (long)M1 * STR;       // 4229136 (elems for fp16, bytes for fp8)
  k_gemm_bt<2><<<dim3(16, 16, NB), 256, 0, stream>>>(F1, F2, E,  E8,  nullptr, nullptr, DD, ab, ab, ob, STR);
  k_gemm_bt<3><<<dim3(16, 16, NB), 256, 0, stream>>>(F2, F1, nullptr, ET8, nullptr, nullptr, DD, ab, ab, ob, STR);

  // E dustbin row/col + ev = 1 + barrier = 0 (one launch)
  const int nfill = NB * NQ * 16 + NB * STR;  // 139328
  k_fillinit<<<(nfill + 255) / 256, 256, 0, stream>>>(E, alpha, ev, bar);

  // persistent Sinkhorn: ONE plain launch, fixed 100 iterations
  k_sink<<<PNWG, PTPB, 0, stream>>>(E8, ET8, eu, ev, alpha, bar);

  // out = E * eu * ev * (m+n)
  k_final<<<NB * M1, 256, 0, stream>>>(E, eu, ev, (float*)d_out);
}